// Round 16
// baseline (126.252 us; speedup 1.0000x reference)
//
#include <hip/hip_runtime.h>
#include <hip/hip_bf16.h>

typedef __attribute__((ext_vector_type(8))) short bf16x8;
typedef __attribute__((ext_vector_type(4))) float f32x4;
typedef __attribute__((ext_vector_type(4))) float f4v;
typedef __attribute__((ext_vector_type(4))) short s4v;

__device__ __forceinline__ short f2bf(float f) {
    union { __hip_bfloat16 h; short s; } u;
    u.h = __float2bfloat16(f);
    return u.s;
}

__device__ __forceinline__ void gload_lds16(const void* g, void* l) {
    __builtin_amdgcn_global_load_lds(
        (const __attribute__((address_space(1))) void*)g,
        (__attribute__((address_space(3))) void*)l,
        16, 0, 0);
}

#define MFMA16(a, b, c) __builtin_amdgcn_mfma_f32_16x16x32_bf16((a), (b), (c), 0, 0, 0)

// ---------------- fused prep: 3x f32->bf16 cvt + per-batch scale ----------------
__global__ void prep_kernel(const float* __restrict__ x,
                            const float* __restrict__ qw,
                            const float* __restrict__ ow,
                            const float* __restrict__ pd,
                            const float* __restrict__ alphap,
                            s4v* __restrict__ xb, s4v* __restrict__ qb,
                            s4v* __restrict__ ob, float* __restrict__ scales) {
    __shared__ float wsum[4];
    if (blockIdx.x >= 2048) {
        int b = blockIdx.x - 2048;
        float s = 0.f;
        for (int i = threadIdx.x; i < 2048; i += 256) s += pd[b * 2048 + i];
        for (int o = 32; o; o >>= 1) s += __shfl_down(s, o);
        if ((threadIdx.x & 63) == 0) wsum[threadIdx.x >> 6] = s;
        __syncthreads();
        if (threadIdx.x == 0) {
            float t = wsum[0] + wsum[1] + wsum[2] + wsum[3];
            float mean = t * (1.0f / 2048.0f);
            float temp = fmaxf(1.0f + alphap[0] * mean, 1e-6f);
            scales[b] = 0.125f * temp;
        }
        return;
    }
    #pragma unroll
    for (int j = 0; j < 4; ++j) {
        int idx = blockIdx.x * 1024 + j * 256 + threadIdx.x;
        const f4v* src;
        s4v* dst;
        int off;
        if (idx < 1048576)      { src = (const f4v*)x;  dst = xb; off = idx; }
        else if (idx < 1835008) { src = (const f4v*)qw; dst = qb; off = idx - 1048576; }
        else                    { src = (const f4v*)ow; dst = ob; off = idx - 1835008; }
        f4v v = src[off];
        s4v o;
        #pragma unroll
        for (int k = 0; k < 4; ++k) o[k] = f2bf(v[k]);
        dst[off] = o;
    }
}

// ---------------- NT GEMM: C[M,N] = A[M,K] * B[N,K]^T + bias ----------------
// T1 XCD swizzle + (256,3): VGPR cap ~168 allows a 3rd block/CU (8->12 waves).
template<int BF16_OUT, int NF>
__global__ __launch_bounds__(256, 3)
void gemm_nt(const __hip_bfloat16* __restrict__ A,
             const __hip_bfloat16* __restrict__ Bw,
             const float* __restrict__ bias,
             void* __restrict__ Cv,
             int M, int N, int K) {
    __shared__ short sA[128 * 64];
    __shared__ short sB[NF * 32 * 64];
    const int tid = threadIdx.x;
    const int wave = tid >> 6, lane = tid & 63;
    const int g = lane >> 4, c = lane & 15;
    const int wr = wave >> 1, wc = wave & 1;

    // XCD swizzle: contiguous tile chunk per XCD (nwg % 8 == 0)
    const int nbx = gridDim.x;
    const int nwg = nbx * gridDim.y;
    int bid = blockIdx.y * nbx + blockIdx.x;
    bid = (bid & 7) * (nwg >> 3) + (bid >> 3);
    const long m0 = (long)(bid / nbx) * 128;
    const long n0 = (long)(bid % nbx) * (NF * 32);

    f32x4 acc[4][NF];
    #pragma unroll
    for (int m = 0; m < 4; ++m)
        #pragma unroll
        for (int n = 0; n < NF; ++n) acc[m][n] = f32x4{0.f, 0.f, 0.f, 0.f};

    for (int k0 = 0; k0 < K; k0 += 64) {
        #pragma unroll
        for (int i = 0; i < 4; ++i) {
            int cb = (i * 4 + wave) * 64;
            int chunk = cb + lane;
            int row = chunk >> 3;
            int sc = ((chunk & 7) * 16) ^ ((row & 7) << 4);
            const char* gA = (const char*)(A + (m0 + row) * (long)K + k0) + sc;
            gload_lds16(gA, (char*)sA + cb * 16);
        }
        #pragma unroll
        for (int i = 0; i < NF; ++i) {
            int cb = (i * 4 + wave) * 64;
            int chunk = cb + lane;
            int row = chunk >> 3;
            int sc = ((chunk & 7) * 16) ^ ((row & 7) << 4);
            const char* gB = (const char*)(Bw + (n0 + row) * (long)K + k0) + sc;
            gload_lds16(gB, (char*)sB + cb * 16);
        }
        __syncthreads();
        #pragma unroll
        for (int s = 0; s < 2; ++s) {
            bf16x8 af[4], bfr[NF];
            #pragma unroll
            for (int m = 0; m < 4; ++m) {
                int row = wr * 64 + m * 16 + c;
                int kb = (s * 64 + g * 16) ^ ((row & 7) << 4);
                af[m] = *(const bf16x8*)((const char*)sA + row * 128 + kb);
            }
            #pragma unroll
            for (int n = 0; n < NF; ++n) {
                int row = wc * (NF * 16) + n * 16 + c;
                int kb = (s * 64 + g * 16) ^ ((row & 7) << 4);
                bfr[n] = *(const bf16x8*)((const char*)sB + row * 128 + kb);
            }
            #pragma unroll
            for (int m = 0; m < 4; ++m)
                #pragma unroll
                for (int n = 0; n < NF; ++n)
                    acc[m][n] = MFMA16(af[m], bfr[n], acc[m][n]);
        }
        __syncthreads();
    }

    #pragma unroll
    for (int m = 0; m < 4; ++m) {
        #pragma unroll
        for (int n = 0; n < NF; ++n) {
            long col = n0 + wc * (NF * 16) + n * 16 + c;
            float bv = bias[col];
            #pragma unroll
            for (int r = 0; r < 4; ++r) {
                long row = m0 + wr * 64 + m * 16 + g * 4 + r;
                float v = acc[m][n][r] + bv;
                if (BF16_OUT)
                    ((__hip_bfloat16*)Cv)[row * N + col] = __float2bfloat16(v);
                else
                    ((float*)Cv)[row * N + col] = v;
            }
        }
    }
}

// ---------------- attention (R15-exact): sP aliased onto sVt[cur^1] ---------
// LDS 34 KB -> 4 blocks/CU; (256,4); defer-max softmax; ones-MFMA row-sum.

__device__ __forceinline__ void compute_tile(
    const short* sKc, const short* sVtc, short* sPw,
    bf16x8 qf0, bf16x8 qf1,
    f32x4 (&acc_o)[4], f32x4& accL, float (&m)[4],
    const float (&ab)[4][4],
    float scale, int qi0, int kv0, bool diag, int g, int c)
{
    f32x4 accs[4];
    const int swz = (c & 7) << 4;
    __builtin_amdgcn_s_setprio(1);
    #pragma unroll
    for (int nf = 0; nf < 4; ++nf) {
        const char* kb = (const char*)sKc + (nf * 16 + c) * 128;
        bf16x8 kf0 = *(const bf16x8*)(kb + ((g * 16) ^ swz));
        bf16x8 kf1 = *(const bf16x8*)(kb + ((64 + g * 16) ^ swz));
        accs[nf] = f32x4{0.f, 0.f, 0.f, 0.f};
        accs[nf] = MFMA16(qf0, kf0, accs[nf]);
        accs[nf] = MFMA16(qf1, kf1, accs[nf]);
    }
    __builtin_amdgcn_s_setprio(0);
    float s[4][4], pmax[4];
    bool ok = true;
    #pragma unroll
    for (int r = 0; r < 4; ++r) {
        int qi = qi0 + r;
        #pragma unroll
        for (int nf = 0; nf < 4; ++nf) {
            float sv = fmaf(accs[nf][r], scale, ab[nf][r]);
            if (diag && (kv0 + nf * 16 + c > qi)) sv = -1e30f;
            s[r][nf] = sv;
        }
        pmax[r] = fmaxf(fmaxf(s[r][0], s[r][1]), fmaxf(s[r][2], s[r][3]));
        ok = ok && (pmax[r] <= m[r] + 8.0f);
    }
    if (!__all(ok)) {   // rare after first tile
        #pragma unroll
        for (int r = 0; r < 4; ++r) {
            float mx = pmax[r];
            mx = fmaxf(mx, __shfl_xor(mx, 1));
            mx = fmaxf(mx, __shfl_xor(mx, 2));
            mx = fmaxf(mx, __shfl_xor(mx, 4));
            mx = fmaxf(mx, __shfl_xor(mx, 8));
            float mn = fmaxf(m[r], mx);
            float alpha = __expf(m[r] - mn);
            m[r] = mn;
            accL[r] *= alpha;
            #pragma unroll
            for (int d = 0; d < 4; ++d) acc_o[d][r] *= alpha;
        }
    }
    #pragma unroll
    for (int r = 0; r < 4; ++r)
        #pragma unroll
        for (int nf = 0; nf < 4; ++nf)
            sPw[(g * 4 + r) * 72 + nf * 16 + c] = f2bf(__expf(s[r][nf] - m[r]));
    asm volatile("s_waitcnt lgkmcnt(0)" ::: "memory");
    bf16x8 pf0 = *(const bf16x8*)((const char*)sPw + c * 144 + g * 16);
    bf16x8 pf1 = *(const bf16x8*)((const char*)sPw + c * 144 + 64 + g * 16);
    const short ONE = 0x3F80;
    const bf16x8 ones = {ONE, ONE, ONE, ONE, ONE, ONE, ONE, ONE};
    __builtin_amdgcn_s_setprio(1);
    accL = MFMA16(pf0, ones, accL);
    accL = MFMA16(pf1, ones, accL);
    #pragma unroll
    for (int d = 0; d < 4; ++d) {
        const char* vb = (const char*)sVtc + (d * 16 + c) * 144;
        bf16x8 vf0 = *(const bf16x8*)(vb + g * 16);
        bf16x8 vf1 = *(const bf16x8*)(vb + 64 + g * 16);
        acc_o[d] = MFMA16(pf0, vf0, acc_o[d]);
        acc_o[d] = MFMA16(pf1, vf1, acc_o[d]);
    }
    __builtin_amdgcn_s_setprio(0);
}

__global__ __launch_bounds__(256, 4)
void attn_kernel(const __hip_bfloat16* __restrict__ qkv,   // [B*L, 3072]
                 const float* __restrict__ alibi,          // [H, L, L]
                 const float* __restrict__ scales,         // [B]
                 __hip_bfloat16* __restrict__ out) {       // [B*L, 1024]
    __shared__ short sK[2][64 * 64];      // 16 KB, swizzled staging
    __shared__ short sVt[2][64 * 72];     // 18 KB, [64 d][64 kv + 8 pad]
    // sP eliminated: wave w uses rows [16w,16w+16) of sVt[cur^1] as P scratch.

    const int h = blockIdx.x, b = blockIdx.y;
    const int qt = 31 - blockIdx.z;       // longest q-tiles dispatched first
    const int nIter = qt + 1;
    const int tid = threadIdx.x;
    const int wave = tid >> 6, lane = tid & 63;
    const int g = lane >> 4, c = lane & 15;
    const float scale = scales[b];
    const long base_bl = (long)b * 2048;

    const int q0 = qt * 64 + wave * 16;

    const __hip_bfloat16* qrow = qkv + (base_bl + q0 + c) * 3072 + h * 64;
    bf16x8 qf0 = *(const bf16x8*)(qrow + g * 8);
    bf16x8 qf1 = *(const bf16x8*)(qrow + 32 + g * 8);

    const __hip_bfloat16* kg = qkv + base_bl * 3072 + 1024 + h * 64;
    const __hip_bfloat16* vg = qkv + base_bl * 3072 + 2048 + h * 64;
    const float* ab_base = alibi + (long)h * 2048 * 2048 + (long)(q0 + g * 4) * 2048;

    const int p2 = tid & 31;
    const int d0 = (tid >> 5) * 8;
    const __hip_bfloat16* vrow = vg + (long)(2 * p2) * 3072 + d0;

    f32x4 acc[4], accL;
    float m[4];
    #pragma unroll
    for (int d = 0; d < 4; ++d) acc[d] = f32x4{0.f, 0.f, 0.f, 0.f};
    accL = f32x4{0.f, 0.f, 0.f, 0.f};
    #pragma unroll
    for (int r = 0; r < 4; ++r) m[r] = -3e38f;

    float ab[4][4], abn[4][4];

    // prologue: stage K(0), V(0), ab(0)
    {
        #pragma unroll
        for (int i = 0; i < 2; ++i) {
            int cb = (i * 4 + wave) * 64;
            int chunk = cb + lane;
            int row = chunk >> 3;
            int sc = ((chunk & 7) * 16) ^ ((row & 7) << 4);
            gload_lds16((const char*)(kg + (long)row * 3072) + sc,
                        (char*)sK[0] + cb * 16);
        }
        bf16x8 va = *(const bf16x8*)vrow;
        bf16x8 vb = *(const bf16x8*)(vrow + 3072);
        #pragma unroll
        for (int j = 0; j < 8; ++j) {
            unsigned pk = ((unsigned)(unsigned short)va[j]) |
                          (((unsigned)(unsigned short)vb[j]) << 16);
            *(unsigned*)((char*)sVt[0] + (d0 + j) * 144 + p2 * 4) = pk;
        }
        #pragma unroll
        for (int nf = 0; nf < 4; ++nf)
            #pragma unroll
            for (int r = 0; r < 4; ++r) {
                ab[nf][r] = ab_base[(long)r * 2048 + nf * 16 + c];
                abn[nf][r] = 0.f;
            }
    }
    __syncthreads();

    for (int t = 0; t < nIter; ++t) {
        const int cur = t & 1;
        const int kv0 = t * 64;
        bf16x8 va, vb;
        const bool haveNext = (t + 1 < nIter);
        if (haveNext) {
            // issue next K tile (direct to LDS) + next V loads (regs, write late)
            #pragma unroll
            for (int i = 0; i < 2; ++i) {
                int cb = (i * 4 + wave) * 64;
                int chunk = cb + lane;
                int row = chunk >> 3;
                int sc = ((chunk & 7) * 16) ^ ((row & 7) << 4);
                gload_lds16((const char*)(kg + (long)(kv0 + 64 + row) * 3072) + sc,
                            (char*)sK[cur ^ 1] + cb * 16);
            }
            const __hip_bfloat16* vp = vrow + (long)(kv0 + 64) * 3072;
            va = *(const bf16x8*)vp;
            vb = *(const bf16x8*)(vp + 3072);
            #pragma unroll
            for (int nf = 0; nf < 4; ++nf)
                #pragma unroll
                for (int r = 0; r < 4; ++r)
                    abn[nf][r] = ab_base[(long)r * 2048 + kv0 + 64 + nf * 16 + c];
        }

        // P scratch = this wave's 16 rows of the idle V buffer (stride 72)
        short* sPw = &sVt[cur ^ 1][0] + wave * (16 * 72);
        compute_tile(sK[cur], sVt[cur], sPw, qf0, qf1,
                     acc, accL, m, ab, scale, q0 + g * 4, kv0, t == qt, g, c);

        if (haveNext) {
            // V-late-write: wave w writes rows [16w,16w+16) — same region as
            // its own P scratch; per-wave in-order DS makes this safe.
            #pragma unroll
            for (int j = 0; j < 8; ++j) {
                unsigned pk = ((unsigned)(unsigned short)va[j]) |
                              (((unsigned)(unsigned short)vb[j]) << 16);
                *(unsigned*)((char*)sVt[cur ^ 1] + (d0 + j) * 144 + p2 * 4) = pk;
            }
        }
        __syncthreads();
        #pragma unroll
        for (int nf = 0; nf < 4; ++nf)
            #pragma unroll
            for (int r = 0; r < 4; ++r)
                ab[nf][r] = abn[nf][r];
    }

    __hip_bfloat16* op = out + (base_bl + q0 + g * 4) * 1024 + h * 64;
    #pragma unroll
    for (int r = 0; r < 4; ++r) {
        float inv = 1.0f / accL[r];
        #pragma unroll
        for (int d = 0; d < 4; ++d)
            op[(long)r * 1024 + d * 16 + c] = __float2bfloat16(acc[d][r] * inv);
    }
}

extern "C" void kernel_launch(void* const* d_in, const int* in_sizes, int n_in,
                              void* d_out, int out_size, void* d_ws, size_t ws_size,
                              hipStream_t stream) {
    const float* x      = (const float*)d_in[0];
    const float* phylo  = (const float*)d_in[1];
    const float* alibi  = (const float*)d_in[2];
    const float* qkv_w  = (const float*)d_in[4];
    const float* qkv_b  = (const float*)d_in[5];
    const float* out_w  = (const float*)d_in[6];
    const float* out_b  = (const float*)d_in[7];
    const float* alphap = (const float*)d_in[8];

    char* ws = (char*)d_ws;
    __hip_bfloat16* xbf   = (__hip_bfloat16*)(ws);                 // 8 MB
    __hip_bfloat16* qwbf  = (__hip_bfloat16*)(ws + (8l << 20));    // 6 MB
    __hip_bfloat16* owbf  = (__hip_bfloat16*)(ws + (14l << 20));   // 2 MB
    __hip_bfloat16* qkvbf = (__hip_bfloat16*)(ws + (16l << 20));   // 24 MB
    __hip_bfloat16* aobf  = (__hip_bfloat16*)(ws + (40l << 20));   // 8 MB
    float* scales         = (float*)(ws + (48l << 20));            // 2 floats

    prep_kernel<<<2050, 256, 0, stream>>>(x, qkv_w, out_w, phylo, alphap,
                                          (s4v*)xbf, (s4v*)qwbf, (s4v*)owbf, scales);

    gemm_nt<1, 4><<<dim3(24, 32), 256, 0, stream>>>(xbf, qwbf, qkv_b, qkvbf,
                                                    4096, 3072, 1024);
    attn_kernel<<<dim3(16, 2, 32), 256, 0, stream>>>(qkvbf, alibi, scales, aobf);
    gemm_nt<0, 2><<<dim3(16, 32), 256, 0, stream>>>(aobf, owbf, out_b, d_out,
                                                    4096, 1024, 1024);
}